// Round 9
// baseline (19.281 us; speedup 1.0000x reference)
//
#include <hip/hip_runtime.h>

#define RR 300
#define NCLS 37
#define COUT 36
#define NSTRIP 5
#define CAP2 128           // max candidates (2/lane); nv>64 already ~impossible
#define SCORE_THR_C 0.1f
#define NMS_THR_C 0.4f

__device__ __forceinline__ int readlanei(int x, int sl) {
    return __builtin_amdgcn_readlane(x, sl);
}

// One wave per (b,c) pair. Greedy NMS via precomputed per-lane suppression
// COLUMNS + ballot resolution: serial chain ~25cy/pivot, no LDS/readlane
// broadcasts inside the scan loop. Kept rows written by their rank-lane.
__global__ __launch_bounds__(64) void det_wave5_kernel(
    const float* __restrict__ rois,
    const float* __restrict__ pred,
    const float* __restrict__ scr,
    const float* __restrict__ iminfo,
    float* __restrict__ out)
{
#pragma clang fp contract(off)
    const int bid  = blockIdx.x;
    const int lane = threadIdx.x;                  // 0..63
    // XCD swizzle: 1152 = 8 * 144; XCD k owns batches [4k, 4k+4).
    const int bc   = (bid & 7) * 144 + (bid >> 3);
    const int b    = bc / COUT;
    const int c    = bc % COUT;
    const int cls  = c + 1;

    __shared__ __align__(16) float csc[CAP2 + 4];  // compact scores + pad
    __shared__ int          cro[CAP2];             // compact orig r
    __shared__ float4       sbx[CAP2];             // sorted boxes
    __shared__ int          sor[CAP2];             // sorted orig r
    __shared__ float        ssc[CAP2];             // sorted scores
    __shared__ unsigned int kpz[80];               // keep flags (320 bytes)

    unsigned char* kp = (unsigned char*)kpz;
    kpz[lane] = 0u;
    if (lane < 16) kpz[64 + lane] = 0u;

    // ---- scores (full gather needed for validity) ----
    float ss[NSTRIP];
    bool  vv[NSTRIP];
    #pragma unroll
    for (int t = 0; t < NSTRIP; ++t) {
        const int r = lane + 64 * t;
        ss[t] = (r < RR) ? scr[(size_t)(b * RR + r) * NCLS + cls] : 0.f;
        vv[t] = (r < RR) && (ss[t] > SCORE_THR_C);
    }

    // ---- compaction (valid set == prefix of stable argsort(-s)) ----
    const unsigned long long lmask = (1ull << lane) - 1ull;
    int pos[NSTRIP];
    int acc = 0;
    #pragma unroll
    for (int t = 0; t < NSTRIP; ++t) {
        const unsigned long long balt = __ballot(vv[t]);
        pos[t] = acc + __popcll(balt & lmask);
        acc   += __popcll(balt);
    }
    int nv = __builtin_amdgcn_readfirstlane(acc);
    if (nv > CAP2) nv = CAP2;

    #pragma unroll
    for (int t = 0; t < NSTRIP; ++t) {
        if (vv[t] && pos[t] < CAP2) {
            csc[pos[t]] = ss[t];
            cro[pos[t]] = lane + 64 * t;
        }
    }
    if (lane < 4) csc[nv + lane] = -1.0f;          // pad for float4 rank loop

    // ---- lazy gather + decode: candidates only ----
    const float Hm1 = iminfo[b * 3 + 0] - 1.0f;
    const float Wm1 = iminfo[b * 3 + 1] - 1.0f;
    const float scl = iminfo[2];   // im_info[0, 2] for ALL batches (per reference)

    const bool has2 = (nv > 64);
    const bool a0 = (lane < nv);
    const bool a1 = has2 && (lane + 64 < nv);

    float  s0 = -2.f, s1 = -2.f;
    int    o0 = 0, o1 = 0;
    float4 b0 = make_float4(0.f, 0.f, 0.f, 0.f), b1 = b0;
    if (a0) {
        s0 = csc[lane];
        o0 = cro[lane];
        const float4 ro = *reinterpret_cast<const float4*>(rois + (size_t)(b * RR + o0) * 4);
        const float4 pp = *reinterpret_cast<const float4*>(pred + (size_t)(b * RR + o0) * (4 * NCLS) + 4 * cls);
        float w  = ro.z - ro.x + 1.0f;
        float h  = ro.w - ro.y + 1.0f;
        float cx = ro.x + 0.5f * w;
        float cy = ro.y + 0.5f * h;
        float dx = pp.x * 0.1f;
        float dy = pp.y * 0.1f;
        float dw = pp.z * 0.2f;
        float dh = pp.w * 0.2f;
        float pcx = dx * w + cx;
        float pcy = dy * h + cy;
        float pw  = expf(dw) * w;
        float ph  = expf(dh) * h;
        b0.x = fminf(fmaxf(pcx - 0.5f * pw, 0.0f), Wm1) / scl;
        b0.y = fminf(fmaxf(pcy - 0.5f * ph, 0.0f), Hm1) / scl;
        b0.z = fminf(fmaxf(pcx + 0.5f * pw, 0.0f), Wm1) / scl;
        b0.w = fminf(fmaxf(pcy + 0.5f * ph, 0.0f), Hm1) / scl;
    }
    if (a1) {
        s1 = csc[lane + 64];
        o1 = cro[lane + 64];
        const float4 ro = *reinterpret_cast<const float4*>(rois + (size_t)(b * RR + o1) * 4);
        const float4 pp = *reinterpret_cast<const float4*>(pred + (size_t)(b * RR + o1) * (4 * NCLS) + 4 * cls);
        float w  = ro.z - ro.x + 1.0f;
        float h  = ro.w - ro.y + 1.0f;
        float cx = ro.x + 0.5f * w;
        float cy = ro.y + 0.5f * h;
        float dx = pp.x * 0.1f;
        float dy = pp.y * 0.1f;
        float dw = pp.z * 0.2f;
        float dh = pp.w * 0.2f;
        float pcx = dx * w + cx;
        float pcy = dy * h + cy;
        float pw  = expf(dw) * w;
        float ph  = expf(dh) * h;
        b1.x = fminf(fmaxf(pcx - 0.5f * pw, 0.0f), Wm1) / scl;
        b1.y = fminf(fmaxf(pcy - 0.5f * ph, 0.0f), Hm1) / scl;
        b1.z = fminf(fmaxf(pcx + 0.5f * pw, 0.0f), Wm1) / scl;
        b1.w = fminf(fmaxf(pcy + 0.5f * ph, 0.0f), Hm1) / scl;
    }

    // ---- stable descending rank (float4 LDS reads; tie by compact pos) ----
    int r0 = 0, r1 = 0;
    const float4* cs4 = reinterpret_cast<const float4*>(&csc[0]);
    const int n4 = (nv + 3) >> 2;
    for (int q4 = 0; q4 < n4; ++q4) {
        const float4 sv = cs4[q4];
        const int qb = q4 * 4;
        r0 += (int)(sv.x > s0) + ((int)(sv.x == s0) & (int)(qb + 0 < lane));
        r0 += (int)(sv.y > s0) + ((int)(sv.y == s0) & (int)(qb + 1 < lane));
        r0 += (int)(sv.z > s0) + ((int)(sv.z == s0) & (int)(qb + 2 < lane));
        r0 += (int)(sv.w > s0) + ((int)(sv.w == s0) & (int)(qb + 3 < lane));
    }
    if (has2) {
        for (int q4 = 0; q4 < n4; ++q4) {
            const float4 sv = cs4[q4];
            const int qb = q4 * 4, me = lane + 64;
            r1 += (int)(sv.x > s1) + ((int)(sv.x == s1) & (int)(qb + 0 < me));
            r1 += (int)(sv.y > s1) + ((int)(sv.y == s1) & (int)(qb + 1 < me));
            r1 += (int)(sv.z > s1) + ((int)(sv.z == s1) & (int)(qb + 2 < me));
            r1 += (int)(sv.w > s1) + ((int)(sv.w == s1) & (int)(qb + 3 < me));
        }
    }

    // ---- scatter by rank; lane now owns sorted candidate `lane` (+64) ----
    if (a0) { sbx[r0] = b0; sor[r0] = o0; ssc[r0] = s0; }
    if (a1) { sbx[r1] = b1; sor[r1] = o1; ssc[r1] = s1; }
    float4 sb0 = make_float4(0.f, 0.f, 0.f, 0.f), sb1 = sb0;
    float  sa0 = 0.f, sa1 = 0.f, sc0 = 0.f, sc1 = 0.f;
    int    so0 = 0, so1 = 0;
    if (a0) { sb0 = sbx[lane];      so0 = sor[lane];      sc0 = ssc[lane];
              sa0 = (sb0.z - sb0.x) * (sb0.w - sb0.y); }
    if (a1) { sb1 = sbx[lane + 64]; so1 = sor[lane + 64]; sc1 = ssc[lane + 64];
              sa1 = (sb1.z - sb1.x) * (sb1.w - sb1.y); }

    // ---- phase A (parallel, pipelined): per-lane suppression COLUMNS ----
    // bit q of cA = "pivot with rank q suppresses my candidate (rank=lane)"
    unsigned long long cAlo = 0ull, cAhi = 0ull, cBlo = 0ull, cBhi = 0ull;
    for (int q = 0; q < nv; ++q) {
        const float4 bq = sbx[q];                  // independent LDS reads
        const float  aq = (bq.z - bq.x) * (bq.w - bq.y);
        {   // candidate A vs pivot q (exact ref IoU expression order)
            float lx = fmaxf(bq.x, sb0.x);
            float ly = fmaxf(bq.y, sb0.y);
            float rx = fminf(bq.z, sb0.z);
            float ry = fminf(bq.w, sb0.w);
            float iw = fmaxf(rx - lx, 0.0f);
            float ih = fmaxf(ry - ly, 0.0f);
            float inter = iw * ih;
            float den = aq + sa0 - inter + 1e-12f;
            float iou = inter / den;
            const bool s = a0 && (q < lane) && (iou > NMS_THR_C);
            if (q < 64) cAlo |= ((unsigned long long)s) << q;
            else        cAhi |= ((unsigned long long)s) << (q - 64);
        }
        if (has2) {
            float lx = fmaxf(bq.x, sb1.x);
            float ly = fmaxf(bq.y, sb1.y);
            float rx = fminf(bq.z, sb1.z);
            float ry = fminf(bq.w, sb1.w);
            float iw = fmaxf(rx - lx, 0.0f);
            float ih = fmaxf(ry - ly, 0.0f);
            float inter = iw * ih;
            float den = aq + sa1 - inter + 1e-12f;
            float iou = inter / den;
            const bool s = a1 && (q < lane + 64) && (iou > NMS_THR_C);
            if (q < 64) cBlo |= ((unsigned long long)s) << q;
            else        cBhi |= ((unsigned long long)s) << (q - 64);
        }
    }

    // ---- resolution: ~6 ops per kept pivot (ctz + shift + ballot) ----
    unsigned long long live0 = (nv >= 64) ? ~0ull : ((1ull << nv) - 1ull);
    unsigned long long live1 = has2 ? ((nv >= 128) ? ~0ull : ((1ull << (nv - 64)) - 1ull)) : 0ull;
    unsigned long long k0 = 0ull, k1 = 0ull;
    while (live0 | live1) {
        if (live0) {
            const int sp = __builtin_ctzll(live0);
            k0 |= 1ull << sp;
            live0 &= ~(1ull << sp);
            live0 &= ~__ballot(((cAlo >> sp) & 1ull) != 0ull);
            if (has2) live1 &= ~__ballot(((cBlo >> sp) & 1ull) != 0ull);
        } else {
            const int sp = __builtin_ctzll(live1);
            k1 |= 1ull << sp;
            live1 &= ~(1ull << sp);
            live1 &= ~__ballot(((cBhi >> sp) & 1ull) != 0ull);
        }
    }

    // ---- publish keep map (c!=0); top row for c==0 is rank 0 ----
    const bool kept0 = a0 && ((k0 >> lane) & 1ull);
    const bool kept1 = a1 && ((k1 >> lane) & 1ull);
    if (kept0) kp[so0] = 1;
    if (kept1) kp[so1] = 1;
    const int top_orig = (nv > 0) ? readlanei(so0, 0) : -1;

    // ---- kept rows: rank-lane writes its own 5 floats ----
    if (kept0 && (c != 0 || lane == 0)) {
        const size_t base = (((size_t)b * COUT + c) * RR + so0) * 5;
        out[base + 0] = fmaxf(sb0.x, 0.0f);
        out[base + 1] = fmaxf(sb0.y, 0.0f);
        out[base + 2] = fmaxf(sb0.z, 0.0f);
        out[base + 3] = fmaxf(sb0.w, 0.0f);
        out[base + 4] = fmaxf(sc0,   0.0f);
    }
    if (kept1 && (c != 0)) {
        const size_t base = (((size_t)b * COUT + c) * RR + so1) * 5;
        out[base + 0] = fmaxf(sb1.x, 0.0f);
        out[base + 1] = fmaxf(sb1.y, 0.0f);
        out[base + 2] = fmaxf(sb1.z, 0.0f);
        out[base + 3] = fmaxf(sb1.w, 0.0f);
        out[base + 4] = fmaxf(sc1,   0.0f);
    }

    // ---- zero rows: strip owner writes zeros for non-kept rows ----
    #pragma unroll
    for (int t = 0; t < NSTRIP; ++t) {
        const int r = lane + 64 * t;
        if (r < RR) {
            const bool keeprow = (c == 0) ? (r == top_orig) : (kp[r] != 0);
            if (!keeprow) {
                const size_t base = (((size_t)b * COUT + c) * RR + r) * 5;
                out[base + 0] = 0.0f;
                out[base + 1] = 0.0f;
                out[base + 2] = 0.0f;
                out[base + 3] = 0.0f;
                out[base + 4] = 0.0f;
            }
        }
    }
}

extern "C" void kernel_launch(void* const* d_in, const int* in_sizes, int n_in,
                              void* d_out, int out_size, void* d_ws, size_t ws_size,
                              hipStream_t stream) {
    const float* rois   = (const float*)d_in[0];
    const float* pred   = (const float*)d_in[1];
    const float* scores = (const float*)d_in[2];
    const float* iminfo = (const float*)d_in[3];
    float* out = (float*)d_out;
    det_wave5_kernel<<<dim3(1152), dim3(64), 0, stream>>>(rois, pred, scores, iminfo, out);
}